// Round 1
// baseline (70.383 us; speedup 1.0000x reference)
//
#include <hip/hip_runtime.h>
#include <hip/hip_bf16.h>
#include <math.h>

// DotDecoder: out[e] = sigmoid( dot(c_feat[src[e]], g_feat[dst[e]]) ), D=64.
// 16 lanes cooperate per edge: each lane loads one float4 (16B) of each
// feature row -> coalesced 256B row reads; shfl_xor reduce within 16 lanes.

__global__ __launch_bounds__(256) void dot_decoder_kernel(
    const float* __restrict__ c_feat,   // [N_CELLS, 64]
    const float* __restrict__ g_feat,   // [N_GENES, 64]
    const int*   __restrict__ src_idx,  // [E]
    const int*   __restrict__ dst_idx,  // [E]
    float*       __restrict__ out,      // [E]
    int nE)
{
    const int lane16 = threadIdx.x & 15;
    int e = (int)((blockIdx.x * (unsigned)blockDim.x + threadIdx.x) >> 4);
    const int estride = (int)((gridDim.x * (unsigned)blockDim.x) >> 4);

    for (; e < nE; e += estride) {
        const int s = src_idx[e];
        const int d = dst_idx[e];
        const float4 a = *reinterpret_cast<const float4*>(c_feat + (size_t)s * 64 + lane16 * 4);
        const float4 b = *reinterpret_cast<const float4*>(g_feat + (size_t)d * 64 + lane16 * 4);
        float p = a.x * b.x + a.y * b.y + a.z * b.z + a.w * b.w;
        // reduce across the 16 lanes of this edge-group
        p += __shfl_xor(p, 1, 16);
        p += __shfl_xor(p, 2, 16);
        p += __shfl_xor(p, 4, 16);
        p += __shfl_xor(p, 8, 16);
        if (lane16 == 0) {
            out[e] = 1.0f / (1.0f + expf(-p));
        }
    }
}

extern "C" void kernel_launch(void* const* d_in, const int* in_sizes, int n_in,
                              void* d_out, int out_size, void* d_ws, size_t ws_size,
                              hipStream_t stream) {
    const float* c_feat = (const float*)d_in[0];
    const float* g_feat = (const float*)d_in[1];
    const int*   src    = (const int*)d_in[2];
    const int*   dst    = (const int*)d_in[3];
    float* out = (float*)d_out;

    const int nE = in_sizes[2];           // 1,000,000 edges
    const int threads = 256;              // 16 edges per block (16 lanes/edge)
    const int edges_per_block = threads / 16;
    const int blocks = (nE + edges_per_block - 1) / edges_per_block;

    dot_decoder_kernel<<<blocks, threads, 0, stream>>>(c_feat, g_feat, src, dst, out, nE);
}

// Round 2
// 60.526 us; speedup vs baseline: 1.1629x; 1.1629x over previous
//
#include <hip/hip_runtime.h>
#include <hip/hip_bf16.h>
#include <math.h>

// DotDecoder: out[e] = sigmoid( dot(c_feat[src[e]], g_feat[dst[e]]) ), D=64.
// 4 lanes cooperate per edge: each lane loads 4 float4s (64B) of each feature
// row -> 8 independent gathers in flight per thread (latency hiding), per-
// instruction the 4 lanes of one edge cover a contiguous 64B chunk (coalesced).
// 2-step shfl_xor reduce within the 4-lane group.

__global__ __launch_bounds__(256) void dot_decoder_kernel(
    const float* __restrict__ c_feat,   // [N_CELLS, 64]
    const float* __restrict__ g_feat,   // [N_GENES, 64]
    const int*   __restrict__ src_idx,  // [E]
    const int*   __restrict__ dst_idx,  // [E]
    float*       __restrict__ out,      // [E]
    int nE)
{
    const int lane4 = threadIdx.x & 3;
    const int e = (int)((blockIdx.x * (unsigned)blockDim.x + threadIdx.x) >> 2);
    if (e >= nE) return;

    const int s = src_idx[e];
    const int d = dst_idx[e];

    const float4* arow = reinterpret_cast<const float4*>(c_feat + (size_t)s * 64) + lane4;
    const float4* brow = reinterpret_cast<const float4*>(g_feat + (size_t)d * 64) + lane4;

    // 8 independent loads — issue all before consuming
    const float4 a0 = arow[0];
    const float4 a1 = arow[4];
    const float4 a2 = arow[8];
    const float4 a3 = arow[12];
    const float4 b0 = brow[0];
    const float4 b1 = brow[4];
    const float4 b2 = brow[8];
    const float4 b3 = brow[12];

    float p = a0.x * b0.x + a0.y * b0.y + a0.z * b0.z + a0.w * b0.w;
    p += a1.x * b1.x + a1.y * b1.y + a1.z * b1.z + a1.w * b1.w;
    p += a2.x * b2.x + a2.y * b2.y + a2.z * b2.z + a2.w * b2.w;
    p += a3.x * b3.x + a3.y * b3.y + a3.z * b3.z + a3.w * b3.w;

    // reduce across the 4 lanes of this edge-group
    p += __shfl_xor(p, 1, 4);
    p += __shfl_xor(p, 2, 4);

    if (lane4 == 0) {
        out[e] = 1.0f / (1.0f + __expf(-p));
    }
}

extern "C" void kernel_launch(void* const* d_in, const int* in_sizes, int n_in,
                              void* d_out, int out_size, void* d_ws, size_t ws_size,
                              hipStream_t stream) {
    const float* c_feat = (const float*)d_in[0];
    const float* g_feat = (const float*)d_in[1];
    const int*   src    = (const int*)d_in[2];
    const int*   dst    = (const int*)d_in[3];
    float* out = (float*)d_out;

    const int nE = in_sizes[2];           // 1,000,000 edges
    const int threads = 256;              // 64 edges per block (4 lanes/edge)
    const int edges_per_block = threads / 4;
    const int blocks = (nE + edges_per_block - 1) / edges_per_block;

    dot_decoder_kernel<<<blocks, threads, 0, stream>>>(c_feat, g_feat, src, dst, out, nE);
}

// Round 3
// 60.399 us; speedup vs baseline: 1.1653x; 1.0021x over previous
//
#include <hip/hip_runtime.h>
#include <hip/hip_bf16.h>
#include <math.h>

// DotDecoder: out[e] = sigmoid( dot(c_feat[src[e]], g_feat[dst[e]]) ), D=64.
// 4 lanes cooperate per edge; each 4-lane group handles TWO edges so each
// thread has 16 independent float4 gathers in flight (latency hiding).
// Per-instruction the 4 lanes of one edge cover a contiguous 64B chunk
// (coalesced). Nontemporal idx loads / out stores keep L2 for feature rows.

__global__ __launch_bounds__(256) void dot_decoder_kernel(
    const float* __restrict__ c_feat,   // [N_CELLS, 64]
    const float* __restrict__ g_feat,   // [N_GENES, 64]
    const int*   __restrict__ src_idx,  // [E]
    const int*   __restrict__ dst_idx,  // [E]
    float*       __restrict__ out,      // [E]
    int nE)
{
    const int lane4 = threadIdx.x & 3;
    const int g = (int)((blockIdx.x * (unsigned)blockDim.x + threadIdx.x) >> 2);
    const int e0 = g * 2;
    if (e0 >= nE) return;
    const bool has2 = (e0 + 1) < nE;
    const int e1 = has2 ? (e0 + 1) : e0;

    const int s0 = __builtin_nontemporal_load(src_idx + e0);
    const int d0 = __builtin_nontemporal_load(dst_idx + e0);
    const int s1 = __builtin_nontemporal_load(src_idx + e1);
    const int d1 = __builtin_nontemporal_load(dst_idx + e1);

    const float4* a0p = reinterpret_cast<const float4*>(c_feat + (size_t)s0 * 64) + lane4;
    const float4* b0p = reinterpret_cast<const float4*>(g_feat + (size_t)d0 * 64) + lane4;
    const float4* a1p = reinterpret_cast<const float4*>(c_feat + (size_t)s1 * 64) + lane4;
    const float4* b1p = reinterpret_cast<const float4*>(g_feat + (size_t)d1 * 64) + lane4;

    // 16 independent loads — issue all before consuming
    const float4 a00 = a0p[0];
    const float4 a01 = a0p[4];
    const float4 a02 = a0p[8];
    const float4 a03 = a0p[12];
    const float4 b00 = b0p[0];
    const float4 b01 = b0p[4];
    const float4 b02 = b0p[8];
    const float4 b03 = b0p[12];
    const float4 a10 = a1p[0];
    const float4 a11 = a1p[4];
    const float4 a12 = a1p[8];
    const float4 a13 = a1p[12];
    const float4 b10 = b1p[0];
    const float4 b11 = b1p[4];
    const float4 b12 = b1p[8];
    const float4 b13 = b1p[12];

    float p0 = a00.x * b00.x + a00.y * b00.y + a00.z * b00.z + a00.w * b00.w;
    p0 += a01.x * b01.x + a01.y * b01.y + a01.z * b01.z + a01.w * b01.w;
    p0 += a02.x * b02.x + a02.y * b02.y + a02.z * b02.z + a02.w * b02.w;
    p0 += a03.x * b03.x + a03.y * b03.y + a03.z * b03.z + a03.w * b03.w;

    float p1 = a10.x * b10.x + a10.y * b10.y + a10.z * b10.z + a10.w * b10.w;
    p1 += a11.x * b11.x + a11.y * b11.y + a11.z * b11.z + a11.w * b11.w;
    p1 += a12.x * b12.x + a12.y * b12.y + a12.z * b12.z + a12.w * b12.w;
    p1 += a13.x * b13.x + a13.y * b13.y + a13.z * b13.z + a13.w * b13.w;

    // reduce across the 4 lanes of this edge-group
    p0 += __shfl_xor(p0, 1, 4);
    p0 += __shfl_xor(p0, 2, 4);
    p1 += __shfl_xor(p1, 1, 4);
    p1 += __shfl_xor(p1, 2, 4);

    if (lane4 == 0) {
        __builtin_nontemporal_store(1.0f / (1.0f + __expf(-p0)), out + e0);
        if (has2) {
            __builtin_nontemporal_store(1.0f / (1.0f + __expf(-p1)), out + e1);
        }
    }
}

extern "C" void kernel_launch(void* const* d_in, const int* in_sizes, int n_in,
                              void* d_out, int out_size, void* d_ws, size_t ws_size,
                              hipStream_t stream) {
    const float* c_feat = (const float*)d_in[0];
    const float* g_feat = (const float*)d_in[1];
    const int*   src    = (const int*)d_in[2];
    const int*   dst    = (const int*)d_in[3];
    float* out = (float*)d_out;

    const int nE = in_sizes[2];           // 1,000,000 edges
    const int threads = 256;              // 64 groups/block, 2 edges/group
    const int edges_per_block = (threads / 4) * 2;
    const int blocks = (nE + edges_per_block - 1) / edges_per_block;

    dot_decoder_kernel<<<blocks, threads, 0, stream>>>(c_feat, g_feat, src, dst, out, nE);
}